// Round 2
// baseline (261.708 us; speedup 1.0000x reference)
//
#include <hip/hip_runtime.h>

// CRF loss (B=1024, T=512, L=62, K=64) for MI355X / gfx950.
// One 64-lane wave per batch (lane j = state j), 1024 blocks -> 1 wave/SIMD:
// runtime = straggler slen x per-step DEPENDENT LATENCY (no TLP exists).
// Linear-domain recursion q_j <- W_j * sum_i q_i E_ij, E = exp(trans).
// Per-step chain, minimized for the DS pipe:
//   h (f16) -> [mem fence] ds_write_b16 [mem fence] -> 8x ds_read_b128 issued
//   back-to-back (two-phase dot: load-all then dot-all, pipelined behind one
//   counted wait) -> 31x v_dot2_f32_f16 (f32 acc) -> same-step exponent renorm
//   (integer bit-extract of ss_lane0's exponent; exact 2^-(ex+6) folded into
//   the W multiply; integer scale accumulator off the chain).
// The asm memory fences pin DS program order: the float4* reads alias the
// _Float16* write (TBAA would otherwise let clang hoist reads above the
// write -> reads uninitialized LDS -> NaN; this was Round-0's failure).
// Numerics are bit-identical to the previously verified 261.8us kernel.
// First step analytic (uniform SMALL -> c_base); final step in log domain.
// Gold path score fused; one atomicAdd(ln2*logZ2 - gold) per block.

#define SMALLF   (-1000.0f)
#define LOG2E_F  1.4426950408889634f
#define LN2_F    0.6931471805599453f

#if defined(__has_builtin)
#if __has_builtin(__builtin_amdgcn_exp2f)
#define EXP2F(x) __builtin_amdgcn_exp2f(x)
#else
#define EXP2F(x) exp2f(x)
#endif
#if __has_builtin(__builtin_amdgcn_logf)
#define LOG2F(x) __builtin_amdgcn_logf(x)
#else
#define LOG2F(x) log2f(x)
#endif
#else
#define EXP2F(x) exp2f(x)
#define LOG2F(x) log2f(x)
#endif

typedef _Float16 h2 __attribute__((ext_vector_type(2)));

#if defined(__has_builtin) && __has_builtin(__builtin_amdgcn_fdot2)
#define FDOT2(a, b, c) __builtin_amdgcn_fdot2((a), (b), (c), false)
#else
#define FDOT2(a, b, c) fmaf((float)(a).x, (float)(b).x, \
                            fmaf((float)(a).y, (float)(b).y, (c)))
#endif

#define MEMFENCE() asm volatile("" ::: "memory")

__device__ __forceinline__ float bcast_first(float v) {
    return __uint_as_float(__builtin_amdgcn_readfirstlane(__float_as_uint(v)));
}

// wave-uniform scale 2^-(ex+6) from ss_lane0; accumulates ex+6 into Ci.
__device__ __forceinline__ float step_scale(float ss, int& Ci) {
    const float s0 = bcast_first(ss);
    const int ex = (int)((__float_as_uint(s0) >> 23) & 0xFF) - 127;  // s0>0 normal
    Ci += ex + 6;
    return __uint_as_float((unsigned)(127 - ex - 6) << 23);          // exact 2^-(ex+6)
}

// ss[lane] = sum_{i<62} h_i * E[i][lane], h from LDS (f16), f32 accumulate.
// TWO-PHASE: all 8 float4 broadcast reads issued first (so they pipeline in
// the DS pipe behind the ds_write_b16), then 31 fdot2 on 4 accumulator
// chains. Pair 31 (rows 62/63) excluded. Caller fences around the write so
// program order write -> reads is guaranteed despite the f16/float4 aliasing.
__device__ __forceinline__ float dot62(const _Float16* __restrict__ hsh,
                                       const h2* __restrict__ Eh) {
    const float4* q4 = (const float4*)hsh;
    float4 v[8];
#pragma unroll
    for (int r = 0; r < 8; ++r) v[r] = q4[r];        // 8x ds_read_b128, no uses
    float a0 = 0.f, a1 = 0.f, a2 = 0.f, a3 = 0.f;
#pragma unroll
    for (int r = 0; r < 8; ++r) {
        const h2 p0 = __builtin_bit_cast(h2, v[r].x);
        const h2 p1 = __builtin_bit_cast(h2, v[r].y);
        const h2 p2 = __builtin_bit_cast(h2, v[r].z);
        const h2 p3 = __builtin_bit_cast(h2, v[r].w);
        a0 = FDOT2(p0, Eh[4 * r + 0], a0);
        a1 = FDOT2(p1, Eh[4 * r + 1], a1);
        a2 = FDOT2(p2, Eh[4 * r + 2], a2);
        if (4 * r + 3 < 31)                          // skip pair 31 (rows 62/63)
            a3 = FDOT2(p3, Eh[4 * r + 3], a3);
    }
    return (a0 + a1) + (a2 + a3);
}

__global__ __launch_bounds__(64, 1) void crf_fused_kernel(
    const float* __restrict__ pred,     // (B,T,L)
    const int*   __restrict__ ref,      // (B,T)
    const int*   __restrict__ seq_len,  // (B,)
    const float* __restrict__ trans,    // (64,64)
    float*       __restrict__ out,      // scalar, pre-zeroed
    int T, int L)
{
    const int b    = blockIdx.x;
    const int lane = threadIdx.x;
    const int slen = seq_len[b];
    const int nmid = slen - 1;              // middle steps t = 2..slen
    const float* prow = pred + (size_t)b * T * L;
    const int*   rrow = ref  + (size_t)b * T;
    const bool mine = (lane < 62);

    __shared__ __align__(16) _Float16 hsh[64];

    // ---- gold score, two-phase gather (indices first, then values)
    int cidx[8], pidx[8];
#pragma unroll
    for (int k = 0; k < 8; ++k) {
        const int t = lane + (k << 6);
        cidx[k] = (t < slen) ? rrow[t] : 0;
        pidx[k] = (t >= 1 && t < slen) ? rrow[t - 1] : 0;
    }
    float gacc = 0.f;
#pragma unroll
    for (int k = 0; k < 8; ++k) {
        const int t = lane + (k << 6);
        if (t < slen) {
            gacc += prow[(size_t)t * L + cidx[k]];
            if (t >= 1) gacc += trans[(pidx[k] << 6) + cidx[k]];
        }
    }
    if (lane == 0)
        gacc += trans[(62 << 6) + rrow[0]] + trans[(rrow[slen - 1] << 6) + 63];

    // ---- E rows 0..61 as half2 pairs (per lane j = column); rows 62/63 are 0
    h2 Eh[31];
    float psum = 0.f;
#pragma unroll
    for (int k = 0; k < 31; ++k) {
        const float e0 = EXP2F(trans[(2 * k + 0) * 64 + lane] * LOG2E_F);
        const float e1 = EXP2F(trans[(2 * k + 1) * 64 + lane] * LOG2E_F);
        Eh[k].x = (_Float16)e0; Eh[k].y = (_Float16)e1;
        psum += e0 + e1;
    }

    // ---- preload obs rows 1..8 (row for step m is m+1, clamped)
    float cur[8];
#pragma unroll
    for (int u = 0; u < 8; ++u) {
        const int row = (u + 1 < T) ? (u + 1) : (T - 1);
        cur[u] = mine ? prow[(size_t)row * L + lane] : 0.f;
    }

    // ---- init (t=1): q = exp2(pred0) * psum; uniform SMALL -> c_base
    int Ci = 0;                              // integer scale accumulator
    const float c_base = SMALLF * LOG2E_F;
    _Float16 hval;
    {
        const float q0 = psum * EXP2F((mine ? prow[lane] : 0.f) * LOG2E_F);
        const float sc = step_scale(q0, Ci);
        hval = (_Float16)(q0 * sc);
    }

    // ---- middle steps m = 0..nmid-1 in chunks of 8 (step m uses row m+1)
    const int nfull = nmid >> 3;
    const int rem   = nmid & 7;
    for (int c = 0; c < nfull; ++c) {
        float W[8], nxt[8];
#pragma unroll
        for (int u = 0; u < 8; ++u)
            W[u] = EXP2F(cur[u] * LOG2E_F);      // off the serial chain
        const int base = 8 * (c + 1) + 1;
#pragma unroll
        for (int u = 0; u < 8; ++u) {            // issue next chunk's loads
            const int row = (base + u < T) ? (base + u) : (T - 1);
            nxt[u] = mine ? prow[(size_t)row * L + lane] : 0.f;
        }
#pragma unroll
        for (int u = 0; u < 8; ++u) {
            MEMFENCE();                          // write stays after prev reads
            hsh[lane] = hval;                    // same-wave DS: in-order
            MEMFENCE();                          // reads stay after write
            const float ss = dot62(hsh, Eh);
            const float sc = step_scale(ss, Ci);
            hval = (_Float16)(ss * (W[u] * sc));
        }
#pragma unroll
        for (int u = 0; u < 8; ++u) cur[u] = nxt[u];
    }

    // ---- remainder middle steps: cur[u] holds row 8*nfull+1+u
    float Wr[7];
#pragma unroll
    for (int u = 0; u < 7; ++u)
        Wr[u] = EXP2F(cur[u] * LOG2E_F);         // precomputed, off-chain
#pragma unroll
    for (int u = 0; u < 7; ++u) {
        if (u < rem) {
            MEMFENCE();
            hsh[lane] = hval;
            MEMFENCE();
            const float ss = dot62(hsh, Eh);
            const float sc = step_scale(ss, Ci);
            hval = (_Float16)(ss * (Wr[u] * sc));
        }
    }

    // ---- final step t = slen+1 in log domain (e_s has +1000)
    {
        MEMFENCE();
        hsh[lane] = hval;
        MEMFENCE();
        const float ssf = dot62(hsh, Eh);        // > 0 on all 64 lanes
        const float pvf = (slen < T) ? cur[rem] : 0.f;  // pred row slen (or r_pad)
        float ob;
        if (lane < 62)       ob = pvf + SMALLF;  // pred/r_pad + e_s SMALL
        else if (lane == 62) ob = SMALLF;        // SMALL + 0
        else                 ob = 0.f;           // SMALL + 1000
        const float alpha = c_base + (float)Ci + LOG2F(ssf) + ob * LOG2E_F;

        float mx = alpha;
#pragma unroll
        for (int k = 32; k >= 1; k >>= 1)
            mx = fmaxf(mx, __shfl_xor(mx, k, 64));
        float pe = EXP2F(alpha - mx);
#pragma unroll
        for (int k = 32; k >= 1; k >>= 1)
            pe += __shfl_xor(pe, k, 64);
#pragma unroll
        for (int k = 32; k >= 1; k >>= 1)
            gacc += __shfl_xor(gacc, k, 64);

        if (lane == 0) {
            const float logZ2 = mx + LOG2F(pe);  // base-2
            atomicAdd(out, LN2_F * logZ2 - gacc);
        }
    }
}

extern "C" void kernel_launch(void* const* d_in, const int* in_sizes, int n_in,
                              void* d_out, int out_size, void* d_ws, size_t ws_size,
                              hipStream_t stream) {
    const float* pred  = (const float*)d_in[0];
    const int*   ref   = (const int*)  d_in[1];
    const int*   slen  = (const int*)  d_in[2];
    const float* trans = (const float*)d_in[3];

    const int B = in_sizes[2];                 // 1024
    const int T = in_sizes[1] / B;             // 512
    const int L = in_sizes[0] / in_sizes[1];   // 62

    hipMemsetAsync(d_out, 0, sizeof(float), stream);
    crf_fused_kernel<<<B, 64, 0, stream>>>(pred, ref, slen, trans,
                                           (float*)d_out, T, L);
}